// Round 1
// baseline (310.877 us; speedup 1.0000x reference)
//
#include <hip/hip_runtime.h>

#define NN   100000
#define KK   32
#define DIN  128
#define DOUT 64
#define NEGV (-9e15f)

// ---------------------------------------------------------------------------
// Kernel A: h = x @ W^T + b   ([N,128] @ [128,64] -> [N,64]), h[0][:] = NEGV
// 256 threads = 4 waves; each wave computes 4 rows x 64 dims (lane = dim).
// W staged in LDS as float4 [64][33] (528B row stride -> conflict-optimal
// ds_read_b128: start banks 4(d+i)%32, 8 accesses/bank = minimum).
// x read with wave-uniform addresses (scalar-load candidates / broadcast).
// ---------------------------------------------------------------------------
__global__ __launch_bounds__(256) void h_kernel(const float* __restrict__ x,
                                                const float* __restrict__ W,
                                                const float* __restrict__ b,
                                                float* __restrict__ h) {
    __shared__ float4 Wl[DOUT][33];   // 33 float4 = 132 floats row stride

    const int t = threadIdx.x;
    const float4* W4 = reinterpret_cast<const float4*>(W);
#pragma unroll
    for (int j = 0; j < 8; ++j) {
        int f = t + j * 256;          // 0..2047 (64*128/4)
        Wl[f >> 5][f & 31] = W4[f];
    }
    __syncthreads();

    const int wid  = __builtin_amdgcn_readfirstlane(t >> 6);
    const int lane = t & 63;
    const int row0 = blockIdx.x * 16 + wid * 4;   // 6250 blocks * 16 = 100000

    const float* xr  = x + (size_t)row0 * DIN;
    const float4* x0p = reinterpret_cast<const float4*>(xr);
    const float4* x1p = reinterpret_cast<const float4*>(xr + DIN);
    const float4* x2p = reinterpret_cast<const float4*>(xr + 2 * DIN);
    const float4* x3p = reinterpret_cast<const float4*>(xr + 3 * DIN);

    const float bd = b[lane];
    float a0 = bd, a1 = bd, a2 = bd, a3 = bd;

#pragma unroll 8
    for (int i = 0; i < 32; ++i) {
        const float4 w4 = Wl[lane][i];
        float4 xv;
        xv = x0p[i];
        a0 = fmaf(w4.x, xv.x, a0); a0 = fmaf(w4.y, xv.y, a0);
        a0 = fmaf(w4.z, xv.z, a0); a0 = fmaf(w4.w, xv.w, a0);
        xv = x1p[i];
        a1 = fmaf(w4.x, xv.x, a1); a1 = fmaf(w4.y, xv.y, a1);
        a1 = fmaf(w4.z, xv.z, a1); a1 = fmaf(w4.w, xv.w, a1);
        xv = x2p[i];
        a2 = fmaf(w4.x, xv.x, a2); a2 = fmaf(w4.y, xv.y, a2);
        a2 = fmaf(w4.z, xv.z, a2); a2 = fmaf(w4.w, xv.w, a2);
        xv = x3p[i];
        a3 = fmaf(w4.x, xv.x, a3); a3 = fmaf(w4.y, xv.y, a3);
        a3 = fmaf(w4.z, xv.z, a3); a3 = fmaf(w4.w, xv.w, a3);
    }

    const size_t o = (size_t)row0 * DOUT + lane;
    h[o]            = (row0 == 0) ? NEGV : a0;   // sentinel row
    h[o + DOUT]     = a1;
    h[o + 2 * DOUT] = a2;
    h[o + 3 * DOUT] = a3;
}

// ---------------------------------------------------------------------------
// Kernel B: per row n:
//   self = sum(h[n]^2); d_k = dot(h[a2a[n,k]], h[n]); m = max(self, d_*)
//   w0 = exp(self-m) / (exp(self-m) + sum_k exp(d_k-m))
//   out[n] = h[n] * w0;  out[0] = 0
// One wave per row (4 rows / 256-thread block). Lane pair (2k,2k+1) splits
// neighbor k's 64-dim dot into two 32-dim halves (8 x float4 gather loads).
// ---------------------------------------------------------------------------
__global__ __launch_bounds__(256) void att_kernel(const float* __restrict__ h,
                                                  const int* __restrict__ a2a,
                                                  float* __restrict__ out) {
    const int t    = threadIdx.x;
    const int wid  = __builtin_amdgcn_readfirstlane(t >> 6);
    const int lane = t & 63;
    const int n    = blockIdx.x * 4 + wid;        // 25000 blocks * 4 = 100000

    const float* hn = h + (size_t)n * DOUT;
    const float hv  = hn[lane];                    // coalesced 256B row read

    // self-dot across all 64 lanes
    float sp = hv * hv;
#pragma unroll
    for (int m = 1; m <= 32; m <<= 1) sp += __shfl_xor(sp, m);

    // neighbor dot: k = lane>>1, half = lane&1 (dims half*32 .. half*32+31)
    const int k    = lane >> 1;
    const int half = lane & 1;
    const int idx  = a2a[n * KK + k];

    const float4* nb = reinterpret_cast<const float4*>(h + (size_t)idx * DOUT) + half * 8;
    const float4* un = reinterpret_cast<const float4*>(hn) + half * 8;

    float d = 0.f;
#pragma unroll
    for (int i = 0; i < 8; ++i) {
        const float4 v = nb[i];
        const float4 u = un[i];
        d = fmaf(v.x, u.x, d);
        d = fmaf(v.y, u.y, d);
        d = fmaf(v.z, u.z, d);
        d = fmaf(v.w, u.w, d);
    }
    d += __shfl_xor(d, 1);    // both lanes of the pair now hold full dot_k

    // max over the 32 neighbor dots (values duplicated per pair) + self
    float m = d;
#pragma unroll
    for (int s = 2; s <= 32; s <<= 1) m = fmaxf(m, __shfl_xor(m, s));
    m = fmaxf(m, sp);

    // sum of exp over neighbors (each k counted twice -> *0.5)
    float e = __expf(d - m);
    float s = e;
#pragma unroll
    for (int q = 1; q <= 32; q <<= 1) s += __shfl_xor(s, q);
    s *= 0.5f;

    const float es = __expf(sp - m);
    const float w0 = es / (es + s);

    float o = hv * w0;
    if (n == 0) o = 0.f;
    out[(size_t)n * DOUT + lane] = o;
}

extern "C" void kernel_launch(void* const* d_in, const int* in_sizes, int n_in,
                              void* d_out, int out_size, void* d_ws, size_t ws_size,
                              hipStream_t stream) {
    const float* x   = (const float*)d_in[0];
    const int*   a2a = (const int*)d_in[1];
    const float* W   = (const float*)d_in[2];
    const float* b   = (const float*)d_in[3];
    float*       out = (float*)d_out;
    float*       h   = (float*)d_ws;   // N*DOUT*4 = 25.6 MB scratch

    h_kernel<<<NN / 16, 256, 0, stream>>>(x, W, b, h);
    att_kernel<<<NN / 4, 256, 0, stream>>>(h, a2a, out);
}

// Round 2
// 204.472 us; speedup vs baseline: 1.5204x; 1.5204x over previous
//
#include <hip/hip_runtime.h>

#define NN   100000
#define KK   32
#define DIN  128
#define DOUT 64
#define NEGV (-9e15f)

// bf16 (stored as ushort) <-> f32 helpers
__device__ __forceinline__ float bflo(unsigned u) { return __uint_as_float(u << 16); }
__device__ __forceinline__ float bfhi(unsigned u) { return __uint_as_float(u & 0xffff0000u); }
__device__ __forceinline__ ushort f2bf(float f) {            // round-to-nearest-even
    unsigned u = __float_as_uint(f);
    return (ushort)((u + 0x7fffu + ((u >> 16) & 1u)) >> 16);
}

// ---------------------------------------------------------------------------
// Kernel A: hb = bf16(x @ W^T + b), hb[0][:] = bf16(NEGV)
// 256 threads / 64 rows per block. x tile + W staged in LDS (exactly 64 KB).
// W is XOR-swizzled so the per-lane ds_read_b128 is bank-optimal (8/bank);
// x reads are wave-uniform broadcasts (conflict-free by definition).
// Each thread: dim d = lane, 16 rows, 2048 FMAs -> VALU-bound ~15 us.
// ---------------------------------------------------------------------------
__global__ __launch_bounds__(256) void h_kernel(const float* __restrict__ x,
                                                const float* __restrict__ W,
                                                const float* __restrict__ b,
                                                ushort* __restrict__ hb) {
    __shared__ float4 Wl[DOUT * 32];   // Wl[d*32 + (k4 ^ (d&7))] = W[d][4k4..4k4+3]
    __shared__ float4 xl[64 * 32];     // xl[row*32 + k4]

    const int t = threadIdx.x;
    const float4* W4 = reinterpret_cast<const float4*>(W);
#pragma unroll
    for (int j = 0; j < 8; ++j) {
        int f = t + j * 256;           // 0..2047
        int d = f >> 5, k4 = f & 31;
        Wl[d * 32 + (k4 ^ (d & 7))] = W4[f];
    }

    const int row0 = blockIdx.x * 64;
    const int nval = ((NN - row0 < 64) ? (NN - row0) : 64) * 32;  // valid float4s
    const float4* x4 = reinterpret_cast<const float4*>(x) + (size_t)row0 * 32;
#pragma unroll
    for (int j = 0; j < 8; ++j) {
        int f = t + j * 256;
        if (f < nval) xl[f] = x4[f];   // coalesced 16B/lane
    }
    __syncthreads();

    const int lane = t & 63;           // output dim d
    const int wg   = t >> 6;           // wave: rows wg*16 .. wg*16+15
    const float bd = b[lane];
    float acc[16];
#pragma unroll
    for (int r = 0; r < 16; ++r) acc[r] = bd;

    const float4* xw   = xl + wg * 16 * 32;
    const float4* wrow = Wl + lane * 32;
    const int sw = lane & 7;

#pragma unroll 4
    for (int k4 = 0; k4 < 32; ++k4) {
        const float4 w4 = wrow[k4 ^ sw];           // bank-optimal b128
#pragma unroll
        for (int r = 0; r < 16; ++r) {
            const float4 xv = xw[r * 32 + k4];     // wave-uniform broadcast
            acc[r] = fmaf(w4.x, xv.x, acc[r]);
            acc[r] = fmaf(w4.y, xv.y, acc[r]);
            acc[r] = fmaf(w4.z, xv.z, acc[r]);
            acc[r] = fmaf(w4.w, xv.w, acc[r]);
        }
    }

#pragma unroll
    for (int r = 0; r < 16; ++r) {
        const int row = row0 + wg * 16 + r;
        if (row < NN) {
            const float v = (row == 0) ? NEGV : acc[r];
            hb[(size_t)row * DOUT + lane] = f2bf(v);   // coalesced 128B stores
        }
    }
}

// ---------------------------------------------------------------------------
// Kernel B: gather-attention from the bf16 table (128B per neighbor row).
// One wave per row; lane pair (2k,2k+1) splits neighbor k's 64-dim dot into
// 32-dim halves (4 x uint4 = 64B per lane). f32 accumulation throughout.
// ---------------------------------------------------------------------------
__global__ __launch_bounds__(256) void att_kernel(const ushort* __restrict__ hb,
                                                  const int* __restrict__ a2a,
                                                  float* __restrict__ out) {
    const int t    = threadIdx.x;
    const int wid  = t >> 6;
    const int lane = t & 63;
    const int n    = blockIdx.x * 4 + wid;          // 25000 blocks * 4

    const ushort* hbn = hb + (size_t)n * DOUT;
    const float hv = bflo((unsigned)hbn[lane]);     // coalesced 128B row read

    // self-dot across 64 lanes
    float sp = hv * hv;
#pragma unroll
    for (int q = 1; q <= 32; q <<= 1) sp += __shfl_xor(sp, q);

    const int k    = lane >> 1;
    const int half = lane & 1;
    const int idx  = a2a[n * KK + k];

    const uint4* nb = reinterpret_cast<const uint4*>(hb + (size_t)idx * DOUT) + half * 4;
    const uint4* un = reinterpret_cast<const uint4*>(hbn) + half * 4;

    float d = 0.f;
#pragma unroll
    for (int i = 0; i < 4; ++i) {
        const uint4 v = nb[i];
        const uint4 u = un[i];
        d = fmaf(bflo(v.x), bflo(u.x), d); d = fmaf(bfhi(v.x), bfhi(u.x), d);
        d = fmaf(bflo(v.y), bflo(u.y), d); d = fmaf(bfhi(v.y), bfhi(u.y), d);
        d = fmaf(bflo(v.z), bflo(u.z), d); d = fmaf(bfhi(v.z), bfhi(u.z), d);
        d = fmaf(bflo(v.w), bflo(u.w), d); d = fmaf(bfhi(v.w), bfhi(u.w), d);
    }
    d += __shfl_xor(d, 1);     // pair now holds full dot_k

    float m = d;
#pragma unroll
    for (int q = 2; q <= 32; q <<= 1) m = fmaxf(m, __shfl_xor(m, q));
    m = fmaxf(m, sp);

    float e = __expf(d - m);
    float s = e;
#pragma unroll
    for (int q = 1; q <= 32; q <<= 1) s += __shfl_xor(s, q);
    s *= 0.5f;                 // each neighbor counted by both lanes of pair

    const float es = __expf(sp - m);
    const float w0 = es / (es + s);

    float o = hv * w0;
    if (n == 0) o = 0.f;
    out[(size_t)n * DOUT + lane] = o;
}

extern "C" void kernel_launch(void* const* d_in, const int* in_sizes, int n_in,
                              void* d_out, int out_size, void* d_ws, size_t ws_size,
                              hipStream_t stream) {
    const float* x   = (const float*)d_in[0];
    const int*   a2a = (const int*)d_in[1];
    const float* W   = (const float*)d_in[2];
    const float* b   = (const float*)d_in[3];
    float*       out = (float*)d_out;
    ushort*      hb  = (ushort*)d_ws;   // N*DOUT*2 = 12.8 MB bf16 table

    h_kernel<<<(NN + 63) / 64, 256, 0, stream>>>(x, W, b, hb);
    att_kernel<<<NN / 4, 256, 0, stream>>>(hb, a2a, out);
}

// Round 3
// 162.602 us; speedup vs baseline: 1.9119x; 1.2575x over previous
//
#include <hip/hip_runtime.h>

#define NN   100000
#define KK   32
#define DIN  128
#define DOUT 64
#define NEGV (-9e15f)

typedef __attribute__((ext_vector_type(8))) short bf16x8;   // 4 VGPRs
typedef __attribute__((ext_vector_type(4))) float f32x4;

__device__ __forceinline__ float bflo(unsigned u) { return __uint_as_float(u << 16); }
__device__ __forceinline__ float bfhi(unsigned u) { return __uint_as_float(u & 0xffff0000u); }
__device__ __forceinline__ ushort f2bf(float f) {            // round-to-nearest-even
    unsigned u = __float_as_uint(f);
    return (ushort)((u + 0x7fffu + ((u >> 16) & 1u)) >> 16);
}
__device__ __forceinline__ unsigned pk2(float a, float b) {  // [bf16(a) | bf16(b)<<16]
    unsigned r;
    asm("v_cvt_pk_bf16_f32 %0, %1, %2" : "=v"(r) : "v"(a), "v"(b));
    return r;
}
__device__ __forceinline__ bf16x8 cvt8(float4 a, float4 b) {
    union { unsigned u[4]; bf16x8 v; } r;
    r.u[0] = pk2(a.x, a.y); r.u[1] = pk2(a.z, a.w);
    r.u[2] = pk2(b.x, b.y); r.u[3] = pk2(b.z, b.w);
    return r.v;
}

// ---------------------------------------------------------------------------
// Kernel A (MFMA): hb = bf16(x @ W^T + b), hb[0][:] = bf16(NEGV)
// No LDS. 4 waves/block, 128 rows/block (2 x 16-row tiles per wave).
// A frag from global x (16 rows x 128B contiguous per load instr, cvt to bf16
// in-reg); B frags (W) loaded once per wave into 64 VGPRs (W is L2-resident).
// mfma_f32_16x16x32_bf16: A lane{row=l&15, k=(l>>4)*8+j}, B lane{col=l&15,
// k=(l>>4)*8+j}, C/D lane{col=l&15, row=(l>>4)*4+reg} (m89/m91-verified).
// ---------------------------------------------------------------------------
__global__ __launch_bounds__(256) void h_kernel(const float* __restrict__ x,
                                                const float* __restrict__ W,
                                                const float* __restrict__ b,
                                                ushort* __restrict__ hb) {
    const int t    = threadIdx.x;
    const int w    = t >> 6;
    const int lane = t & 63;
    const int lr   = lane & 15;     // frag row (A) / col (B, C)
    const int lg   = lane >> 4;     // k-group

    // B fragments: B[k][n] = W[n][k]; n = ct*16+lr, k = ks*32 + lg*8 + j
    bf16x8 Bf[4][4];
    const float* wp = W + (size_t)lr * DIN + lg * 8;
#pragma unroll
    for (int ct = 0; ct < 4; ++ct)
#pragma unroll
        for (int ks = 0; ks < 4; ++ks) {
            const float* p = wp + ct * 16 * DIN + ks * 32;
            Bf[ct][ks] = cvt8(*(const float4*)p, *(const float4*)(p + 4));
        }

    float bias[4];
#pragma unroll
    for (int ct = 0; ct < 4; ++ct) bias[ct] = b[ct * 16 + lr];

    const int base = blockIdx.x * 128 + w * 16;     // 782 blocks * 128 >= NN
#pragma unroll
    for (int tile = 0; tile < 2; ++tile) {
        const int row0 = base + tile * 64;

        int ar = row0 + lr;                          // A row for this lane
        if (ar > NN - 1) ar = NN - 1;                // clamp (result discarded)
        const float* xp = x + (size_t)ar * DIN + lg * 8;

        bf16x8 Af[4];
#pragma unroll
        for (int ks = 0; ks < 4; ++ks)
            Af[ks] = cvt8(*(const float4*)(xp + ks * 32),
                          *(const float4*)(xp + ks * 32 + 4));

        f32x4 acc[4] = {{0.f,0.f,0.f,0.f},{0.f,0.f,0.f,0.f},
                        {0.f,0.f,0.f,0.f},{0.f,0.f,0.f,0.f}};
#pragma unroll
        for (int ct = 0; ct < 4; ++ct)
#pragma unroll
            for (int ks = 0; ks < 4; ++ks)
                acc[ct] = __builtin_amdgcn_mfma_f32_16x16x32_bf16(
                    Af[ks], Bf[ct][ks], acc[ct], 0, 0, 0);

#pragma unroll
        for (int ct = 0; ct < 4; ++ct)
#pragma unroll
            for (int j = 0; j < 4; ++j) {
                const int m = row0 + lg * 4 + j;
                if (m < NN) {
                    const float v = (m == 0) ? NEGV : (acc[ct][j] + bias[ct]);
                    hb[(size_t)m * DOUT + ct * 16 + lr] = f2bf(v);
                }
            }
    }
}

// ---------------------------------------------------------------------------
// Kernel B: gather-attention from the bf16 table (128B per neighbor row).
// One wave per row; lane pair (2k,2k+1) splits neighbor k's 64-dim dot into
// 32-dim halves (4 x uint4 = 64B per lane). f32 accumulation throughout.
// ---------------------------------------------------------------------------
__global__ __launch_bounds__(256) void att_kernel(const ushort* __restrict__ hb,
                                                  const int* __restrict__ a2a,
                                                  float* __restrict__ out) {
    const int t    = threadIdx.x;
    const int wid  = t >> 6;
    const int lane = t & 63;
    const int n    = blockIdx.x * 4 + wid;          // 25000 blocks * 4

    const ushort* hbn = hb + (size_t)n * DOUT;
    const float hv = bflo((unsigned)hbn[lane]);     // coalesced 128B row read

    float sp = hv * hv;                              // self-dot, 64 lanes
#pragma unroll
    for (int q = 1; q <= 32; q <<= 1) sp += __shfl_xor(sp, q);

    const int k    = lane >> 1;
    const int half = lane & 1;
    const int idx  = a2a[n * KK + k];

    const uint4* nb = reinterpret_cast<const uint4*>(hb + (size_t)idx * DOUT) + half * 4;
    const uint4* un = reinterpret_cast<const uint4*>(hbn) + half * 4;

    float d = 0.f;
#pragma unroll
    for (int i = 0; i < 4; ++i) {
        const uint4 v = nb[i];
        const uint4 u = un[i];
        d = fmaf(bflo(v.x), bflo(u.x), d); d = fmaf(bfhi(v.x), bfhi(u.x), d);
        d = fmaf(bflo(v.y), bflo(u.y), d); d = fmaf(bfhi(v.y), bfhi(u.y), d);
        d = fmaf(bflo(v.z), bflo(u.z), d); d = fmaf(bfhi(v.z), bfhi(u.z), d);
        d = fmaf(bflo(v.w), bflo(u.w), d); d = fmaf(bfhi(v.w), bfhi(u.w), d);
    }
    d += __shfl_xor(d, 1);     // pair now holds full dot_k

    float m = d;
#pragma unroll
    for (int q = 2; q <= 32; q <<= 1) m = fmaxf(m, __shfl_xor(m, q));
    m = fmaxf(m, sp);

    float e = __expf(d - m);
    float s = e;
#pragma unroll
    for (int q = 1; q <= 32; q <<= 1) s += __shfl_xor(s, q);
    s *= 0.5f;                 // each neighbor counted by both lanes of pair

    const float es = __expf(sp - m);
    const float w0 = es / (es + s);

    float o = hv * w0;
    if (n == 0) o = 0.f;
    out[(size_t)n * DOUT + lane] = o;
}

extern "C" void kernel_launch(void* const* d_in, const int* in_sizes, int n_in,
                              void* d_out, int out_size, void* d_ws, size_t ws_size,
                              hipStream_t stream) {
    const float* x   = (const float*)d_in[0];
    const int*   a2a = (const int*)d_in[1];
    const float* W   = (const float*)d_in[2];
    const float* b   = (const float*)d_in[3];
    float*       out = (float*)d_out;
    ushort*      hb  = (ushort*)d_ws;   // N*DOUT*2 = 12.8 MB bf16 table

    h_kernel<<<(NN + 127) / 128, 256, 0, stream>>>(x, W, b, hb);
    att_kernel<<<NN / 4, 256, 0, stream>>>(hb, a2a, out);
}